// Round 4
// baseline (336.920 us; speedup 1.0000x reference)
//
#include <hip/hip_runtime.h>
#include <hip/hip_bf16.h>

// B=2048, T=32, V=1024, D=256
// idx = argmin_v (c2[t][v] - 2*x.c); embed = gathered codebook rows.
// Round 4: barrier-free MFMA loop. B held in registers (64 cols x K=256 bf16
// per wave), loaded lane-coalesced from a prep-permuted bf16 codebook. A is
// LDS-resident (staged once). Running per-(row,wave) min in LDS (wave-owned
// slots). Wave-local threshold + MARGIN is a superset of the exact margin set
// (bf16 score error <= ~0.7 worst case; margin 8). Exact fp32 rescore + gather.

#define B_ 2048
#define T_ 32
#define V_ 1024
#define D_ 256
#define BT 128
#define CAND_MAX 2048
#define MARGIN 8.0f

typedef __attribute__((ext_vector_type(8))) short short8;   // 8 bf16 = 4 VGPR
typedef __attribute__((ext_vector_type(4))) float f32x4;

__device__ __forceinline__ unsigned short f2bf(float f) {
    unsigned u = __builtin_bit_cast(unsigned, f);
    unsigned r = u + 0x7FFFu + ((u >> 16) & 1u);
    return (unsigned short)(r >> 16);
}

__device__ __forceinline__ short8 pack8(float4 a, float4 b) {
    short8 r;
    r[0] = (short)f2bf(a.x); r[1] = (short)f2bf(a.y);
    r[2] = (short)f2bf(a.z); r[3] = (short)f2bf(a.w);
    r[4] = (short)f2bf(b.x); r[5] = (short)f2bf(b.y);
    r[6] = (short)f2bf(b.z); r[7] = (short)f2bf(b.w);
    return r;
}

// ---- prep: cbs[t][cg][kc][q][ln] = bf16 chunk (col cg*16+ln, k kc*32+q*8..+8)
// One 16B chunk == exactly one lane's B-fragment piece -> vq loads are
// perfectly coalesced dwordx4 (lane stride 16B). c2 fused (shfl reduce).
__global__ void prep_kernel(const float* __restrict__ cb, float* __restrict__ c2,
                            unsigned short* __restrict__ cbs) {
    const int t = blockIdx.x >> 6, cg = blockIdx.x & 63;
    __shared__ float c2p[4][16];
    const int tid = threadIdx.x, wave = tid >> 6, lane = tid & 63;
    float part = 0.f;
    short8* outp = (short8*)cbs + (size_t)(t * 64 + cg) * 512;
    #pragma unroll
    for (int j = 0; j < 2; ++j) {
        const int lin = tid + j * 256;            // chunk id: kc*64 + q*16 + ln
        const int kc = lin >> 6, qq = (lin >> 4) & 3, l = lin & 15;
        const float* src = cb + ((size_t)t * V_ + cg * 16 + l) * D_ + kc * 32 + qq * 8;
        const float4 a = ((const float4*)src)[0], b = ((const float4*)src)[1];
        part += a.x*a.x + a.y*a.y + a.z*a.z + a.w*a.w
              + b.x*b.x + b.y*b.y + b.z*b.z + b.w*b.w;
        outp[lin] = pack8(a, b);                  // coalesced: addr = lin*16B
    }
    part += __shfl_xor(part, 16, 64);             // combine q groups (same ln)
    part += __shfl_xor(part, 32, 64);
    if (lane < 16) c2p[wave][lane] = part;        // this wave covered kc={w,w+4}
    __syncthreads();
    if (tid < 16)
        c2[t * V_ + cg * 16 + tid] = c2p[0][tid] + c2p[1][tid] + c2p[2][tid] + c2p[3][tid];
}

// fallback prep (ws too small for cbs): c2 only
__global__ void c2_kernel(const float* __restrict__ cb, float* __restrict__ c2) {
    const int row = blockIdx.x * 4 + (threadIdx.x >> 6);
    const int lane = threadIdx.x & 63;
    const float4 v = ((const float4*)(cb + (size_t)row * D_))[lane];
    float s = v.x * v.x + v.y * v.y + v.z * v.z + v.w * v.w;
    #pragma unroll
    for (int off = 32; off; off >>= 1) s += __shfl_down(s, off, 64);
    if (lane == 0) c2[row] = s;
}

// ---------------- main ----------------
__global__ __launch_bounds__(256, 2)
void vq_kernel(const float* __restrict__ x, const float* __restrict__ cb,
               const float* __restrict__ c2, const unsigned short* __restrict__ cbs,
               float* __restrict__ out, int use_swz) {
    const int t  = blockIdx.x;
    const int b0 = blockIdx.y * BT;

    // LDS = 65536 + 2048 + 1024 + 8192 + 4 = 76,804 B -> 2 blocks/CU
    __shared__ short8 A_lds[4096];                 // 128 rows x 32 granules, XOR(r&15)
    __shared__ float  minW[BT * 4];                // running min per (row, wave)
    __shared__ unsigned long long result[BT];
    __shared__ unsigned s_cand[CAND_MAX];
    __shared__ unsigned s_cnt;

    const int tid = threadIdx.x;
    const int wave = tid >> 6, lane = tid & 63;
    const int q = lane >> 4, ln = lane & 15;

    if (tid < BT) result[tid] = ~0ULL;
    minW[tid] = 3.4e38f; minW[tid + 256] = 3.4e38f;
    if (tid == 0) s_cnt = 0;

    // stage A once (fp32 -> bf16, XOR swizzle) — only barrier-paired staging
    #pragma unroll
    for (int i = 0; i < 16; ++i) {
        int gid = i * 256 + tid, r = gid >> 5, g = gid & 31;
        const float4* src = (const float4*)(x + (((size_t)(b0 + r)) * T_ + t) * D_ + g * 8);
        A_lds[r * 32 + (g ^ (r & 15))] = pack8(src[0], src[1]);
    }
    __syncthreads();

    for (int vp = 0; vp < 4; ++vp) {               // 4 passes x 256 v-cols
        // ---- B fragments for this wave's 64 cols, full K=256, into registers
        short8 breg[4][8];
        if (use_swz) {
            const short8* bp = (const short8*)cbs
                + (size_t)(t * 64 + vp * 16 + wave * 4) * 512 + lane;
            #pragma unroll
            for (int nt = 0; nt < 4; ++nt)
                #pragma unroll
                for (int kc = 0; kc < 8; ++kc)
                    breg[nt][kc] = bp[nt * 512 + kc * 64];   // coalesced dwordx4
        } else {
            #pragma unroll
            for (int nt = 0; nt < 4; ++nt) {
                const int col = vp * 256 + wave * 64 + nt * 16 + ln;
                const float* cp = cb + ((size_t)t * V_ + col) * D_ + q * 8;
                #pragma unroll
                for (int kc = 0; kc < 8; ++kc) {
                    const float4 a = ((const float4*)(cp + kc * 32))[0];
                    const float4 b = ((const float4*)(cp + kc * 32))[1];
                    breg[nt][kc] = pack8(a, b);
                }
            }
        }
        float cc[4];
        #pragma unroll
        for (int nt = 0; nt < 4; ++nt)
            cc[nt] = c2[t * V_ + vp * 256 + wave * 64 + nt * 16 + ln];

        #pragma unroll 1
        for (int mt = 0; mt < 8; ++mt) {           // all 128 rows, barrier-free
            f32x4 acc[4];
            #pragma unroll
            for (int nt = 0; nt < 4; ++nt) acc[nt] = (f32x4){0.f, 0.f, 0.f, 0.f};
            #pragma unroll
            for (int kh = 0; kh < 2; ++kh) {
                short8 af[4];
                #pragma unroll
                for (int j2 = 0; j2 < 4; ++j2) {
                    const int kc = kh * 4 + j2;
                    af[j2] = A_lds[(mt * 16 + ln) * 32 + ((kc * 4 + q) ^ ln)];
                }
                #pragma unroll
                for (int j2 = 0; j2 < 4; ++j2)
                    #pragma unroll
                    for (int nt = 0; nt < 4; ++nt)
                        acc[nt] = __builtin_amdgcn_mfma_f32_16x16x32_bf16(
                            af[j2], breg[nt][kh * 4 + j2], acc[nt], 0, 0, 0);
            }
            // epilogue: scores, wave-local row min, collect candidates
            float s[4][4];
            #pragma unroll
            for (int nt = 0; nt < 4; ++nt)
                #pragma unroll
                for (int i = 0; i < 4; ++i)
                    s[nt][i] = fmaf(-2.0f, acc[nt][i], cc[nt]);
            #pragma unroll
            for (int i = 0; i < 4; ++i) {
                float mn = fminf(fminf(s[0][i], s[1][i]), fminf(s[2][i], s[3][i]));
                mn = fminf(mn, __shfl_xor(mn, 1, 64));
                mn = fminf(mn, __shfl_xor(mn, 2, 64));
                mn = fminf(mn, __shfl_xor(mn, 4, 64));
                mn = fminf(mn, __shfl_xor(mn, 8, 64));
                const int row = mt * 16 + q * 4 + i;
                const float old = minW[row * 4 + wave];   // wave-own slot
                const float thr = fminf(old, mn) + MARGIN;
                #pragma unroll
                for (int nt = 0; nt < 4; ++nt) {
                    if (s[nt][i] < thr) {
                        const int v = vp * 256 + wave * 64 + nt * 16 + ln;
                        const unsigned pos = atomicAdd(&s_cnt, 1u);
                        if (pos < CAND_MAX) s_cand[pos] = (unsigned)((row << 10) | v);
                    }
                }
                if (ln == 0) minW[row * 4 + wave] = fminf(old, mn);
            }
        }
    }

    // ---- exact fp32 rescore of candidates (16-lane groups)
    __syncthreads();
    const unsigned ncand = min(s_cnt, (unsigned)CAND_MAX);
    const int grp = tid >> 4, l16 = tid & 15;
    for (unsigned ci = grp; ci < ncand; ci += 16) {
        const unsigned e = s_cand[ci];
        const int row = e >> 10, v = e & 1023;
        const float* xr = x + (((size_t)(b0 + row)) * T_ + t) * D_ + l16 * 16;
        const float* cr = cb + ((size_t)t * V_ + v) * D_ + l16 * 16;
        float dot = 0.f;
        #pragma unroll
        for (int j = 0; j < 4; ++j) {
            float4 a = *(const float4*)(xr + j * 4);
            float4 b = *(const float4*)(cr + j * 4);
            dot = fmaf(a.x, b.x, dot); dot = fmaf(a.y, b.y, dot);
            dot = fmaf(a.z, b.z, dot); dot = fmaf(a.w, b.w, dot);
        }
        dot += __shfl_xor(dot, 1, 64);
        dot += __shfl_xor(dot, 2, 64);
        dot += __shfl_xor(dot, 4, 64);
        dot += __shfl_xor(dot, 8, 64);
        if (l16 == 0) {
            float sc = fmaf(-2.0f, dot, c2[t * V_ + v]);
            unsigned u = __builtin_bit_cast(unsigned, sc);
            u = (u & 0x80000000u) ? ~u : (u | 0x80000000u);   // sortable fp32
            atomicMin(&result[row], ((unsigned long long)u << 32) | (unsigned)v);
        }
    }
    __syncthreads();

    if (tid < BT)
        out[(size_t)B_ * T_ * D_ + (size_t)(b0 + tid) * T_ + t] =
            (float)(int)(result[tid] & 1023u);

    // ---- fused gather
    #pragma unroll
    for (int i = 0; i < 32; ++i) {
        const int row = wave * 32 + i;
        const int idx = (int)(result[row] & 1023u);
        const float4 src = *(const float4*)(cb + ((size_t)t * V_ + idx) * D_ + lane * 4);
        *(float4*)(out + (((size_t)(b0 + row)) * T_ + t) * D_ + lane * 4) = src;
    }
}

extern "C" void kernel_launch(void* const* d_in, const int* in_sizes, int n_in,
                              void* d_out, int out_size, void* d_ws, size_t ws_size,
                              hipStream_t stream) {
    const float* x  = (const float*)d_in[0];   // (B,T,D)
    const float* cb = (const float*)d_in[1];   // (T,V,D)
    float* out = (float*)d_out;                // embed fp32 ++ idx (as float)
    float* c2  = (float*)d_ws;                 // 32768 floats = 128 KB
    unsigned short* cbs = (unsigned short*)((char*)d_ws + 131072);  // 16 MB
    const size_t NEED = 131072 + (size_t)T_ * V_ * D_ * 2;
    const int use_swz = (ws_size >= NEED) ? 1 : 0;

    if (use_swz) prep_kernel<<<dim3(T_ * V_ / 16), 256, 0, stream>>>(cb, c2, cbs);
    else         c2_kernel<<<dim3(T_ * V_ / 4), 256, 0, stream>>>(cb, c2);
    vq_kernel<<<dim3(T_, B_ / BT), 256, 0, stream>>>(x, cb, c2, cbs, out, use_swz);
}